// Round 16
// baseline (1683.024 us; speedup 1.0000x reference)
//
#include <hip/hip_runtime.h>
#include <hip/hip_bf16.h>

// ---------------------------------------------------------------------------
// HybridCnnLnn R16: attack the 300us idle (R15: busy 783, idle 300).
//  1) 1 batch/block, grid 512, 1024 thr -> 2 blocks/CU (32 waves/CU): cross-
//     block overlap fills barrier bubbles + serial sections.
//  2) r12 split to fit 2 blocks in LDS: i<64 in LDS (64KB, h<4, full unroll),
//     i>=64 streamed from L2 (h>=4, unroll 8; 1.7 TB/s/XCD << 4.3 ceiling).
//  3) lgkmcnt-only barriers (asm): no vmcnt(0) drain -> feats/S4/r12 loads
//     ride through barriers (R15: HBM xt loads stalled every wave each t).
// Per-batch arithmetic bit-identical to R15 (absmax 0.0).
// Toxic list: ext-vector v2f (R11), full-unroll global loads (R13),
// >64-VGPR live set (R7-R9).
// ---------------------------------------------------------------------------

#define L2E 1.4426950408889634f

// LDS-visibility barrier WITHOUT vmcnt drain (global loads stay in flight).
#define BARRIER_LDS() asm volatile("s_waitcnt lgkmcnt(0)\n\ts_barrier" ::: "memory")

// ---------------- prep: fold params, native [i][j] layout (identity) -------
__global__ __launch_bounds__(256)
void prep_kernel(const float* __restrict__ smu, const float* __restrict__ ssig,
                 const float* __restrict__ sW,  const float* __restrict__ serev,
                 const float* __restrict__ mu,  const float* __restrict__ sig,
                 const float* __restrict__ W,   const float* __restrict__ erev,
                 const float* __restrict__ in_w, const float* __restrict__ in_b,
                 float2* __restrict__ R12, float* __restrict__ VT,
                 float4* __restrict__ S4) {
  int idx = blockIdx.x * 256 + threadIdx.x;      // 64 blocks x 256 = 16384
  int i = idx >> 7;
  float r1 = sig[idx] * L2E;
  R12[idx] = make_float2(r1, mu[idx] * r1);      // z = r2 - r1*v
  VT[idx]  = W[idx] * erev[idx];                 // |erev|=1 -> |VT| = W
  float ss = ssig[idx] * L2E;
  S4[idx] = make_float4(ss * in_w[i], (smu[idx] - in_b[i]) * ss,
                        sW[idx] * serev[idx], 0.f);
}

// ----------------------------- conv1 (k=5, tiled) --------------------------
// x [512,256,24] -> P1 [512,64,128] ([b][co][t']), relu+maxpool2 fused
__launch_bounds__(512)
__global__ void conv1_kernel(const float* __restrict__ x, const float* __restrict__ w1,
                             const float* __restrict__ b1, float* __restrict__ P1) {
  __shared__ float xs[6240];                     // rows t in [-2,258), 24 ch
  int tid = threadIdx.x, b = blockIdx.x;
  const float* xb = x + (size_t)b * 6144;
  for (int idx = tid; idx < 6144; idx += 512) xs[idx + 48] = xb[idx];
  if (tid < 48) { xs[tid] = 0.f; xs[6192 + tid] = 0.f; }
  __syncthreads();
  int tp = tid & 127, cq = tid >> 7;             // 128 pooled t x 4 co-quarters
  float acc0[16], acc1[16];
#pragma unroll
  for (int n = 0; n < 16; n++) { float bb = b1[cq * 16 + n]; acc0[n] = bb; acc1[n] = bb; }
  for (int cic = 0; cic < 3; cic++) {            // ci chunks of 8
    float p[6][8];
#pragma unroll
    for (int r = 0; r < 6; r++) {
      const float* row = &xs[(2 * tp + r) * 24 + cic * 8];
      float4 a = *(const float4*)row;
      float4 c = *(const float4*)(row + 4);
      p[r][0] = a.x; p[r][1] = a.y; p[r][2] = a.z; p[r][3] = a.w;
      p[r][4] = c.x; p[r][5] = c.y; p[r][6] = c.z; p[r][7] = c.w;
    }
#pragma unroll
    for (int n = 0; n < 16; n++) {
      const float* wr = w1 + (cq * 16 + n) * 120 + cic * 40;  // uniform -> s_load
#pragma unroll
      for (int c = 0; c < 8; c++) {
#pragma unroll
        for (int kk = 0; kk < 5; kk++) {
          float w = wr[c * 5 + kk];
          acc0[n] = fmaf(p[kk][c],     w, acc0[n]);
          acc1[n] = fmaf(p[kk + 1][c], w, acc1[n]);
        }
      }
    }
  }
  float* pb = P1 + (size_t)b * 8192;
#pragma unroll
  for (int n = 0; n < 16; n++)
    pb[(cq * 16 + n) * 128 + tp] = fmaxf(fmaxf(acc0[n], acc1[n]), 0.f);
}

// ----------------------------- conv2 (k=3, tiled) --------------------------
// P1 [512,64,128] -> feats [512,64,128] laid out [b][t'][co]
__launch_bounds__(512)
__global__ void conv2_kernel(const float* __restrict__ P1, const float* __restrict__ w2,
                             const float* __restrict__ b2, float* __restrict__ feats) {
  __shared__ float xs[8450];                     // [t+1][ci], stride 65
  int tid = threadIdx.x, b = blockIdx.x;
  const float* pb = P1 + (size_t)b * 8192;
  for (int idx = tid; idx < 8192; idx += 512) {
    int ci = idx >> 7, t = idx & 127;
    xs[(t + 1) * 65 + ci] = pb[idx];
  }
  if (tid < 65) { xs[tid] = 0.f; xs[129 * 65 + tid] = 0.f; }
  __syncthreads();
  int tp = tid & 63, cq = tid >> 6;              // 64 pooled t x 8 co-octants
  float acc0[16], acc1[16];
#pragma unroll
  for (int n = 0; n < 16; n++) { float bb = b2[cq * 16 + n]; acc0[n] = bb; acc1[n] = bb; }
  for (int cic = 0; cic < 8; cic++) {            // ci chunks of 8
    float p[4][8];
#pragma unroll
    for (int r = 0; r < 4; r++)
#pragma unroll
      for (int c = 0; c < 8; c++)
        p[r][c] = xs[(2 * tp + r) * 65 + cic * 8 + c];
#pragma unroll
    for (int n = 0; n < 16; n++) {
      const float* wr = w2 + (cq * 16 + n) * 192 + cic * 24;  // native [co][ci][kk]
#pragma unroll
      for (int c = 0; c < 8; c++) {
#pragma unroll
        for (int kk = 0; kk < 3; kk++) {
          float w = wr[c * 3 + kk];
          acc0[n] = fmaf(p[kk][c],     w, acc0[n]);
          acc1[n] = fmaf(p[kk + 1][c], w, acc1[n]);
        }
      }
    }
  }
  __syncthreads();                               // reuse xs as [tp][co]
#pragma unroll
  for (int n = 0; n < 16; n += 4) {
    float4 v;
    v.x = fmaxf(fmaxf(acc0[n],     acc1[n]),     0.f);
    v.y = fmaxf(fmaxf(acc0[n + 1], acc1[n + 1]), 0.f);
    v.z = fmaxf(fmaxf(acc0[n + 2], acc1[n + 2]), 0.f);
    v.w = fmaxf(fmaxf(acc0[n + 3], acc1[n + 3]), 0.f);
    *(float4*)&xs[tp * 128 + cq * 16 + n] = v;
  }
  __syncthreads();
  float* fb = feats + (size_t)b * 8192;
  for (int idx = tid; idx < 8192; idx += 512) fb[idx] = xs[idx];
}

// --------------------------- LTC recurrence + head -------------------------
// 1 batch/block, grid 512 = 2 blocks/CU. block = 1024 thr: j = tid&127,
// h = tid>>7 (i-octant, i in [16h,16h+16)). r12: i<64 in LDS (64KB), i>=64
// streamed from L2. vw in 16 VGPRs; S4 streamed. lgkmcnt-only barriers.
__launch_bounds__(1024)
__global__ void lnn_kernel(const float2* __restrict__ R12, const float* __restrict__ VT,
                           const float4* __restrict__ S4,
                           const float* __restrict__ feats,
                           const float* __restrict__ cm_t, const float* __restrict__ gleak,
                           const float* __restrict__ vleak,
                           const float* __restrict__ fc1_w, const float* __restrict__ fc1_b,
                           const float* __restrict__ fc2_w, const float* __restrict__ fc2_b,
                           float* __restrict__ out) {
  __shared__ float2 r12lds[8192];                // 64KB: (r1,r2)[i<64][j]
  __shared__ float2 psum[8][128];                // 8KB: (n,d) partials
  __shared__ float vs[128];
  __shared__ float xt[128];
  __shared__ float red[64];
  int tid = threadIdx.x;
  int j = tid & 127, h = tid >> 7;               // h in [0,8)
  int bb = blockIdx.x;                           // one batch per block

  // stage lower-half (r1,r2) into LDS (8 coalesced float2 iters)
  for (int idx = tid; idx < 8192; idx += 1024) r12lds[idx] = R12[idx];

  // vw -> VGPRs (16 regs; coalesced over j)
  float vw[16];
#pragma unroll
  for (int n = 0; n < 16; n++) vw[n] = VT[(16 * h + n) * 128 + j];

  float cmj = cm_t[j], glk = gleak[j];
  float gvl = glk * vleak[j], cgl = cmj + glk;
  float vj = 0.f;
  if (tid < 128) vs[j] = 0.f;
  float xn = 0.f;
  if (tid < 128) xn = feats[(size_t)bb * 8192 + j];   // t=0 prefetch
  BARRIER_LDS();

  for (int t = 0; t < 64; t++) {
    if (tid < 128) xt[j] = xn;                   // consume prefetched value
    BARRIER_LDS();
    if (t < 63 && tid < 128)                     // prefetch t+1; rides through
      xn = feats[(size_t)bb * 8192 + (t + 1) * 128 + j];  // lgkm barriers

    // ---- sensory partials (packed S4 streamed from L2; unroll 8) ----
    float sn = 0.f, sd = 0.f;
    {
      float n0 = 0.f, d0 = 0.f;
      const float4* sp = S4 + (size_t)(16 * h) * 128 + j;
#pragma unroll 8
      for (int n = 0; n < 16; n++) {
        float4 s = sp[n * 128];
        float xv = xt[16 * h + n];
        float q = __builtin_amdgcn_rcpf(1.f + __builtin_amdgcn_exp2f(fmaf(-s.x, xv, s.y)));
        n0 = fmaf(s.z, q, n0); d0 = fmaf(fabsf(s.z), q, d0);
      }
      psum[h][j] = make_float2(n0, d0);
    }
    BARRIER_LDS();
    if (h == 0) {                                // wave-uniform branch
      float2 a0 = psum[0][j], a1 = psum[1][j], a2 = psum[2][j], a3 = psum[3][j];
      float2 a4 = psum[4][j], a5 = psum[5][j], a6 = psum[6][j], a7 = psum[7][j];
      sn = a0.x + a1.x + a2.x + a3.x + a4.x + a5.x + a6.x + a7.x;
      sd = a0.y + a1.y + a2.y + a3.y + a4.y + a5.y + a6.y + a7.y;
    }
    BARRIER_LDS();                               // psum reusable after this

    // ---- 6 semi-implicit ODE unfolds ----
#pragma unroll 1
    for (int u = 0; u < 6; u++) {
      float n0 = 0.f, d0 = 0.f;
      if (h < 4) {                               // LDS half (full unroll)
        const float2* mp = &r12lds[(16 * h) * 128 + j];
#pragma unroll
        for (int n = 0; n < 16; n++) {
          float2 rr = mp[n * 128];
          float v2 = vs[16 * h + n];             // broadcast read
          float q = __builtin_amdgcn_rcpf(1.f + __builtin_amdgcn_exp2f(fmaf(-rr.x, v2, rr.y)));
          n0 = fmaf(vw[n], q, n0); d0 = fmaf(fabsf(vw[n]), q, d0);
        }
      } else {                                   // L2-streamed half (unroll 8)
        const float2* gp = R12 + (size_t)(16 * h) * 128 + j;
#pragma unroll 8
        for (int n = 0; n < 16; n++) {
          float2 rr = gp[n * 128];
          float v2 = vs[16 * h + n];
          float q = __builtin_amdgcn_rcpf(1.f + __builtin_amdgcn_exp2f(fmaf(-rr.x, v2, rr.y)));
          n0 = fmaf(vw[n], q, n0); d0 = fmaf(fabsf(vw[n]), q, d0);
        }
      }
      psum[h][j] = make_float2(n0, d0);
      BARRIER_LDS();
      if (h == 0) {                              // wave-uniform serial section
        float2 a0 = psum[0][j], a1 = psum[1][j], a2 = psum[2][j], a3 = psum[3][j];
        float2 a4 = psum[4][j], a5 = psum[5][j], a6 = psum[6][j], a7 = psum[7][j];
        float wn = sn + a0.x + a1.x + a2.x + a3.x + a4.x + a5.x + a6.x + a7.x;
        float wd = sd + a0.y + a1.y + a2.y + a3.y + a4.y + a5.y + a6.y + a7.y;
        float den = cgl + wd;                    // NR rcp (den>1.5; ~1ulp)
        float iv = __builtin_amdgcn_rcpf(den); iv = iv * fmaf(-den, iv, 2.f);
        vj = (fmaf(cmj, vj, gvl) + wn) * iv;
        vs[j] = vj;
      }
      BARRIER_LDS();
    }
  }

  // ---- MLP head ----
  if (tid < 64) {
    float acc = fc1_b[tid];
    for (int u = 0; u < 128; u++)
      acc = fmaf(vs[u], fc1_w[tid * 128 + u], acc);
    red[tid] = fmaxf(acc, 0.f) * fc2_w[tid];
  }
  BARRIER_LDS();
  if (tid == 0) {
    float s = fc2_b[0];
    for (int d = 0; d < 64; d++) s += red[d];
    out[bb] = s;
  }
}

// ------------------------------- launcher ----------------------------------
extern "C" void kernel_launch(void* const* d_in, const int* in_sizes, int n_in,
                              void* d_out, int out_size, void* d_ws, size_t ws_size,
                              hipStream_t stream) {
  (void)in_sizes; (void)n_in; (void)out_size; (void)ws_size;
  char* ws = (char*)d_ws;
  // Proven 32MB envelope, time-multiplexed:
  //   P1 [0,16M) live conv1->conv2; tables [0,448K) after conv2 (prep);
  //   feats [16M,32M) live conv2->lnn.
  float*  P1   = (float*)(ws);
  float*  feats= (float*)(ws + (16 << 20));
  float2* R12  = (float2*)(ws + 0);             // 128KB
  float*  VT   = (float*)(ws + (128 << 10));    // 64KB
  float4* S4   = (float4*)(ws + (192 << 10));   // 256KB -> ends 448KB

  conv1_kernel<<<512, 512, 0, stream>>>((const float*)d_in[0],
      (const float*)d_in[1], (const float*)d_in[2], P1);
  conv2_kernel<<<512, 512, 0, stream>>>(P1,
      (const float*)d_in[3], (const float*)d_in[4], feats);
  prep_kernel<<<64, 256, 0, stream>>>(
      (const float*)d_in[7], (const float*)d_in[8],
      (const float*)d_in[9], (const float*)d_in[10],
      (const float*)d_in[11], (const float*)d_in[12],
      (const float*)d_in[13], (const float*)d_in[14],
      (const float*)d_in[5], (const float*)d_in[6],
      R12, VT, S4);
  lnn_kernel<<<512, 1024, 0, stream>>>(R12, VT, S4, feats,
      (const float*)d_in[17], (const float*)d_in[16], (const float*)d_in[15],
      (const float*)d_in[18], (const float*)d_in[19],
      (const float*)d_in[20], (const float*)d_in[21],
      (float*)d_out);
}